// Round 5
// baseline (457.782 us; speedup 1.0000x reference)
//
#include <hip/hip_runtime.h>
#include <math.h>

#define F1 16
#define F2 8
#define C1 4   // x1 accumulator replicas (cuts same-address atomic multiplicity 4x)
#define C2 4   // x2 accumulator replicas

typedef float f32x4 __attribute__((ext_vector_type(4)));

// Per edge: count in-degree (int atomics) + default edge value 1.0.
// Per node (id <= N): rowptr[id] = lower_bound(src, id)  (src is sorted,
// since edge_index = np.nonzero(A) is row-major ordered).
__global__ void k_prep(const int* __restrict__ src, const int* __restrict__ dst,
                       int* __restrict__ degi, float* __restrict__ val,
                       int* __restrict__ rowptr, int E, int N) {
    int id = blockIdx.x * blockDim.x + threadIdx.x;
    if (id < E) {
        atomicAdd(&degi[dst[id]], 1);
        val[id] = 1.0f;
    }
    if (id <= N) {
        int lo = 0, hi = E;
        while (lo < hi) {
            int mid = (lo + hi) >> 1;
            if (src[mid] < id) lo = mid + 1; else hi = mid;
        }
        rowptr[id] = lo;
    }
}

// dinv[i] = rsqrt(deg_i + 1);  Wn1[i,f] = dinv[i] * W1[i,f]
__global__ void k_wn1(const int* __restrict__ degi, const float* __restrict__ W1,
                      float* __restrict__ dinv, float* __restrict__ Wn1, int N) {
    int id = blockIdx.x * blockDim.x + threadIdx.x;
    if (id < N * F1) {
        int i = id >> 4;
        float di = rsqrtf((float)(degi[i] + 1));
        if ((id & (F1 - 1)) == 0) dinv[i] = di;
        Wn1[id] = di * W1[id];
    }
}

// conv1 aggregation: x1[e&3][dst,f] += Wn1[src,f].  Pure load+atomic —
// normalization hoisted out; replicas cut same-address serialization.
__global__ void k_conv1_edges(const int* __restrict__ src, const int* __restrict__ dst,
                              const float* __restrict__ Wn1, float* __restrict__ x1,
                              int E, int N) {
    int id = blockIdx.x * blockDim.x + threadIdx.x;
    int e = id >> 4;
    int f = id & (F1 - 1);
    if (e < E) {
        int s = src[e], d = dst[e];
        float* rep = x1 + (long)(e & (C1 - 1)) * F1 * N;
        atomicAdd(&rep[(long)d * F1 + f], Wn1[(long)s * F1 + f]);
    }
}

// Per (node, out-feature): r = relu(dinv_i*(sum_c x1[c] + Wn1_i) + b1);
// h2n[i,g] = dinv_i * sum_f r[f]*W2[f,g]
__global__ void k_layer1(const float* __restrict__ dinv, const float* __restrict__ b1,
                         const float* __restrict__ Wn1, const float* __restrict__ W2,
                         const float* __restrict__ x1, float* __restrict__ h2n, int N) {
    int id = blockIdx.x * blockDim.x + threadIdx.x;
    if (id < N * F2) {
        int i = id >> 3;        // node
        int g = id & (F2 - 1);  // out feature
        float di = dinv[i];
        float acc = 0.0f;
        #pragma unroll
        for (int f = 0; f < F1; ++f) {
            long off = (long)i * F1 + f;
            float sum = Wn1[off];
            #pragma unroll
            for (int c = 0; c < C1; ++c) sum += x1[(long)c * F1 * N + off];
            float v = di * sum + b1[f];
            v = v > 0.0f ? v : 0.0f;
            acc += v * W2[f * F2 + g];
        }
        h2n[(long)i * F2 + g] = di * acc;
    }
}

// conv2 aggregation: x2[e&3][dst,g] += h2n[src,g].
__global__ void k_conv2_edges(const int* __restrict__ src, const int* __restrict__ dst,
                              const float* __restrict__ h2n, float* __restrict__ x2,
                              int E, int N) {
    int id = blockIdx.x * blockDim.x + threadIdx.x;
    int e = id >> 3;
    int g = id & (F2 - 1);
    if (e < E) {
        int s = src[e], d = dst[e];
        float* rep = x2 + (long)(e & (C2 - 1)) * F2 * N;
        atomicAdd(&rep[(long)d * F2 + g], h2n[(long)s * F2 + g]);
    }
}

// Per undirected edge: finish conv2 (x = relu(dinv*(sum_c x2[c] + h2n) + b2)),
// score, sigmoid; write orient into sparse val[] at the two directed-edge
// slots (binary search over each row's sorted dst list).
__global__ void k_orient2(const int2* __restrict__ ue, const float* __restrict__ x2,
                          const float* __restrict__ h2n, const float* __restrict__ dinv,
                          const float* __restrict__ b2, const float* __restrict__ Wfc,
                          const float* __restrict__ bfc, const int* __restrict__ rowptr,
                          const int* __restrict__ dst, float* __restrict__ val,
                          int U, int N) {
    int k = blockIdx.x * blockDim.x + threadIdx.x;
    if (k >= U) return;
    int2 e = ue[k];
    int u = e.x, v = e.y;
    float du = dinv[u], dv = dinv[v];
    float s = bfc[0];
    #pragma unroll
    for (int g = 0; g < F2; ++g) {
        float su = h2n[(long)u * F2 + g];
        float sv = h2n[(long)v * F2 + g];
        #pragma unroll
        for (int c = 0; c < C2; ++c) {
            su += x2[(long)c * F2 * N + (long)u * F2 + g];
            sv += x2[(long)c * F2 * N + (long)v * F2 + g];
        }
        float xu = du * su + b2[g];
        float xv = dv * sv + b2[g];
        xu = xu > 0.0f ? xu : 0.0f;
        xv = xv > 0.0f ? xv : 0.0f;
        s += xu * Wfc[g] + xv * Wfc[F2 + g];
    }
    float o = 1.0f / (1.0f + expf(-s));
    int lo = rowptr[u], hi = rowptr[u + 1];
    while (lo < hi) { int mid = (lo + hi) >> 1; if (dst[mid] < v) lo = mid + 1; else hi = mid; }
    if (lo < rowptr[u + 1] && dst[lo] == v) val[lo] = o;
    lo = rowptr[v]; hi = rowptr[v + 1];
    while (lo < hi) { int mid = (lo + hi) >> 1; if (dst[mid] < u) lo = mid + 1; else hi = mid; }
    if (lo < rowptr[v + 1] && dst[lo] == u) val[lo] = 1.0f - o;
}

// Single-pass output: one workgroup per row. Zero the row with coalesced f32x4
// stores (lines stay L2-resident), barrier, then overwrite this row's edge
// positions from val[].  Output HBM traffic = N*N*4 bytes, written once.
__global__ void __launch_bounds__(256) k_writeout(const int* __restrict__ rowptr,
                                                  const int* __restrict__ dst,
                                                  const float* __restrict__ val,
                                                  float* __restrict__ out, int N) {
    int row = blockIdx.x;
    int t = threadIdx.x;
    int n4 = N >> 2;
    f32x4* out4 = (f32x4*)(out + (long)row * N);
    f32x4 z = {0.0f, 0.0f, 0.0f, 0.0f};
    for (int j = t; j < n4; j += 256) out4[j] = z;
    __syncthreads();
    int r0 = rowptr[row], r1 = rowptr[row + 1];
    float* orow = out + (long)row * N;
    for (int k = r0 + t; k < r1; k += 256) orow[dst[k]] = val[k];
}

extern "C" void kernel_launch(void* const* d_in, const int* in_sizes, int n_in,
                              void* d_out, int out_size, void* d_ws, size_t ws_size,
                              hipStream_t stream) {
    const float* W1  = (const float*)d_in[1];
    const float* b1  = (const float*)d_in[2];
    const float* W2  = (const float*)d_in[3];
    const float* b2  = (const float*)d_in[4];
    const float* Wfc = (const float*)d_in[5];
    const float* bfc = (const float*)d_in[6];
    const int* edge_index = (const int*)d_in[7];
    const int2* und       = (const int2*)d_in[8];

    int N = in_sizes[1] / F1;      // 8192
    int E = in_sizes[7] / 2;
    int U = in_sizes[8] / 2;
    const int* src = edge_index;
    const int* dst = edge_index + E;

    // ws layout (4B words):
    //   zeroed:  degi[N] | x1[C1][16N] | x2[C2][8N]      (= (1+64+32)N words)
    //   written: dinv[N] | Wn1[16N] | h2n[8N] | rowptr[N+1] | val[E]
    int*   degi   = (int*)d_ws;
    float* x1     = (float*)(degi + N);
    float* x2     = x1 + (long)C1 * F1 * N;
    float* dinv   = x2 + (long)C2 * F2 * N;
    float* Wn1    = dinv + N;
    float* h2n    = Wn1 + (long)F1 * N;
    int*   rowptr = (int*)(h2n + (long)F2 * N);
    float* val    = (float*)(rowptr + N + 1);

    const int B = 256;
    long nz = (long)N * (1 + C1 * F1 + C2 * F2);   // words to zero
    (void)hipMemsetAsync(d_ws, 0, (size_t)nz * sizeof(float), stream);

    // degree count + val=1 + rowptr
    {
        int work = (E > N + 1) ? E : (N + 1);
        k_prep<<<(work + B - 1) / B, B, 0, stream>>>(src, dst, degi, val, rowptr, E, N);
    }
    // dinv + normalized W1
    k_wn1<<<(N * F1 + B - 1) / B, B, 0, stream>>>(degi, W1, dinv, Wn1, N);
    // conv1 aggregation (replicated atomic scatter, no per-edge math)
    {
        long work = (long)E * F1;
        k_conv1_edges<<<(int)((work + B - 1) / B), B, 0, stream>>>(src, dst, Wn1, x1, E, N);
    }
    // layer1: replica-reduce + relu + 16x8 matmul -> h2n (dinv-scaled)
    k_layer1<<<(N * F2 + B - 1) / B, B, 0, stream>>>(dinv, b1, Wn1, W2, x1, h2n, N);
    // conv2 aggregation (replicated atomic scatter)
    {
        long work = (long)E * F2;
        k_conv2_edges<<<(int)((work + B - 1) / B), B, 0, stream>>>(src, dst, h2n, x2, E, N);
    }
    // orient scoring -> sparse val[]
    k_orient2<<<(U + B - 1) / B, B, 0, stream>>>(und, x2, h2n, dinv, b2, Wfc, bfc,
                                                 rowptr, dst, val, U, N);
    // single-pass output construction
    k_writeout<<<N, B, 0, stream>>>(rowptr, dst, val, (float*)d_out, N);
}

// Round 6
// 445.545 us; speedup vs baseline: 1.0275x; 1.0275x over previous
//
#include <hip/hip_runtime.h>
#include <math.h>

#define F1 16
#define F2 8

typedef float f32x4 __attribute__((ext_vector_type(4)));

// Per edge: count in-degree (int atomics).
// Per node (id <= N): rowptr[id] = lower_bound(src, id)  (src is sorted,
// since edge_index = np.nonzero(A) is row-major ordered).
__global__ void k_prep(const int* __restrict__ src, const int* __restrict__ dst,
                       int* __restrict__ degi, int* __restrict__ rowptr, int E, int N) {
    int id = blockIdx.x * blockDim.x + threadIdx.x;
    if (id < E) atomicAdd(&degi[dst[id]], 1);
    if (id <= N) {
        int lo = 0, hi = E;
        while (lo < hi) {
            int mid = (lo + hi) >> 1;
            if (src[mid] < id) lo = mid + 1; else hi = mid;
        }
        rowptr[id] = lo;
    }
}

// dinv[i] = rsqrt(deg_i + 1);  Wn1[i,f] = dinv[i] * W1[i,f]
__global__ void k_wn1(const int* __restrict__ degi, const float* __restrict__ W1,
                      float* __restrict__ dinv, float* __restrict__ Wn1, int N) {
    int id = blockIdx.x * blockDim.x + threadIdx.x;
    if (id < N * F1) {
        int i = id >> 4;
        float di = rsqrtf((float)(degi[i] + 1));
        if ((id & (F1 - 1)) == 0) dinv[i] = di;
        Wn1[id] = di * W1[id];
    }
}

// conv1 aggregation: x1[dst,f] += Wn1[src,f] (norm hoisted; x1 pre-zeroed).
__global__ void k_conv1_edges(const int* __restrict__ src, const int* __restrict__ dst,
                              const float* __restrict__ Wn1, float* __restrict__ x1, int E) {
    int id = blockIdx.x * blockDim.x + threadIdx.x;
    int e = id >> 4;
    int f = id & (F1 - 1);
    if (e < E) {
        int s = src[e], d = dst[e];
        atomicAdd(&x1[(long)d * F1 + f], Wn1[(long)s * F1 + f]);
    }
}

// Per (node, out-feature): r = relu(dinv_i*(x1 + Wn1_i) + b1);
// h2n[i,g] = dinv_i * sum_f r[f]*W2[f,g]
__global__ void k_layer1(const float* __restrict__ dinv, const float* __restrict__ b1,
                         const float* __restrict__ Wn1, const float* __restrict__ W2,
                         const float* __restrict__ x1, float* __restrict__ h2n, int N) {
    int id = blockIdx.x * blockDim.x + threadIdx.x;
    if (id < N * F2) {
        int i = id >> 3;
        int g = id & (F2 - 1);
        float di = dinv[i];
        float acc = 0.0f;
        #pragma unroll
        for (int f = 0; f < F1; ++f) {
            long off = (long)i * F1 + f;
            float v = di * (x1[off] + Wn1[off]) + b1[f];
            v = v > 0.0f ? v : 0.0f;
            acc += v * W2[f * F2 + g];
        }
        h2n[(long)i * F2 + g] = di * acc;
    }
}

// conv2 aggregation: x2[dst,g] += h2n[src,g] (x2 pre-zeroed).
__global__ void k_conv2_edges(const int* __restrict__ src, const int* __restrict__ dst,
                              const float* __restrict__ h2n, float* __restrict__ x2, int E) {
    int id = blockIdx.x * blockDim.x + threadIdx.x;
    int e = id >> 3;
    int g = id & (F2 - 1);
    if (e < E) {
        int s = src[e], d = dst[e];
        atomicAdd(&x2[(long)d * F2 + g], h2n[(long)s * F2 + g]);
    }
}

// Finish conv2 per node: xf[i,g] = relu(dinv_i*(x2 + h2n_i) + b2).
__global__ void k_xf(const float* __restrict__ dinv, const float* __restrict__ b2,
                     const float* __restrict__ h2n, const float* __restrict__ x2,
                     float* __restrict__ xf, int N) {
    int id = blockIdx.x * blockDim.x + threadIdx.x;
    if (id < N * F2) {
        int i = id >> 3;
        int g = id & (F2 - 1);
        float x = dinv[i] * (x2[id] + h2n[id]) + b2[g];
        xf[id] = x > 0.0f ? x : 0.0f;
    }
}

// Single-pass output: one workgroup per row. Build the row in LDS (zero +
// per-edge value computed inline: 1.0 if reverse edge absent, else orient
// sigmoid from final embeddings), then stream the finished row to HBM with
// non-temporal f32x4 stores. Output HBM traffic = N*N*4 bytes, exactly once,
// no L2 RMW dependency. Orient value for (r,c): with u=min, v=max roles,
// o = sigmoid(concat(xf[u],xf[v]) @ Wfc + bfc); slot gets o if r==u else 1-o.
__global__ void __launch_bounds__(256) k_writeout(const int* __restrict__ rowptr,
                                                  const int* __restrict__ dst,
                                                  const float* __restrict__ xf,
                                                  const float* __restrict__ Wfc,
                                                  const float* __restrict__ bfc,
                                                  float* __restrict__ out, int N) {
    extern __shared__ float row[];
    int r = blockIdx.x;
    int t = threadIdx.x;
    int n4 = N >> 2;
    f32x4* row4 = (f32x4*)row;
    f32x4 z = {0.0f, 0.0f, 0.0f, 0.0f};
    for (int j = t; j < n4; j += 256) row4[j] = z;
    __syncthreads();
    int r0 = rowptr[r], r1 = rowptr[r + 1];
    for (int k = r0 + t; k < r1; k += 256) {
        int c = dst[k];
        // does the reverse edge (c -> ... row c contains r) exist?
        int lo = rowptr[c], hi = rowptr[c + 1];
        while (lo < hi) { int mid = (lo + hi) >> 1; if (dst[mid] < r) lo = mid + 1; else hi = mid; }
        float w = 1.0f;
        if (lo < rowptr[c + 1] && dst[lo] == r) {
            int u = r < c ? r : c;
            int v = r < c ? c : r;
            const f32x4* x4 = (const f32x4*)xf;
            f32x4 ua = x4[(long)u * 2], ub = x4[(long)u * 2 + 1];
            f32x4 va = x4[(long)v * 2], vb = x4[(long)v * 2 + 1];
            const f32x4* w4 = (const f32x4*)Wfc;
            f32x4 wu0 = w4[0], wu1 = w4[1], wv0 = w4[2], wv1 = w4[3];
            float s = bfc[0];
            #pragma unroll
            for (int g = 0; g < 4; ++g)
                s += ua[g] * wu0[g] + ub[g] * wu1[g] + va[g] * wv0[g] + vb[g] * wv1[g];
            float o = 1.0f / (1.0f + expf(-s));
            w = (r == u) ? o : 1.0f - o;
        }
        row[c] = w;
    }
    __syncthreads();
    f32x4* out4 = (f32x4*)(out + (long)r * N);
    for (int j = t; j < n4; j += 256) {
        __builtin_nontemporal_store(row4[j], &out4[j]);
    }
}

extern "C" void kernel_launch(void* const* d_in, const int* in_sizes, int n_in,
                              void* d_out, int out_size, void* d_ws, size_t ws_size,
                              hipStream_t stream) {
    const float* W1  = (const float*)d_in[1];
    const float* b1  = (const float*)d_in[2];
    const float* W2  = (const float*)d_in[3];
    const float* b2  = (const float*)d_in[4];
    const float* Wfc = (const float*)d_in[5];
    const float* bfc = (const float*)d_in[6];
    const int* edge_index = (const int*)d_in[7];

    int N = in_sizes[1] / F1;      // 8192
    int E = in_sizes[7] / 2;
    const int* src = edge_index;
    const int* dst = edge_index + E;

    // ws layout (4B words):
    //   zeroed:  degi[N] | x1[16N] | x2[8N]                (25N words = 800 KB)
    //   written: dinv[N] | Wn1[16N] | h2n[8N] | xf[8N] | rowptr[N+1]
    int*   degi   = (int*)d_ws;
    float* x1     = (float*)(degi + N);
    float* x2     = x1 + (long)F1 * N;
    float* dinv   = x2 + (long)F2 * N;
    float* Wn1    = dinv + N;
    float* h2n    = Wn1 + (long)F1 * N;
    float* xf     = h2n + (long)F2 * N;
    int*   rowptr = (int*)(xf + (long)F2 * N);

    const int B = 256;

    (void)hipMemsetAsync(d_ws, 0, (size_t)N * (1 + F1 + F2) * sizeof(float), stream);

    // degree count + rowptr (binary search over sorted src)
    {
        int work = (E > N + 1) ? E : (N + 1);
        k_prep<<<(work + B - 1) / B, B, 0, stream>>>(src, dst, degi, rowptr, E, N);
    }
    // dinv + normalized W1
    k_wn1<<<(N * F1 + B - 1) / B, B, 0, stream>>>(degi, W1, dinv, Wn1, N);
    // conv1 aggregation (atomic scatter)
    {
        long work = (long)E * F1;
        k_conv1_edges<<<(int)((work + B - 1) / B), B, 0, stream>>>(src, dst, Wn1, x1, E);
    }
    // layer1 -> h2n (dinv-scaled hidden)
    k_layer1<<<(N * F2 + B - 1) / B, B, 0, stream>>>(dinv, b1, Wn1, W2, x1, h2n, N);
    // conv2 aggregation (atomic scatter)
    {
        long work = (long)E * F2;
        k_conv2_edges<<<(int)((work + B - 1) / B), B, 0, stream>>>(src, dst, h2n, x2, E);
    }
    // finish conv2 per node -> final embeddings
    k_xf<<<(N * F2 + B - 1) / B, B, 0, stream>>>(dinv, b2, h2n, x2, xf, N);
    // fused orient + single-pass LDS-staged output
    k_writeout<<<N, B, (size_t)N * sizeof(float), stream>>>(rowptr, dst, xf, Wfc, bfc,
                                                            (float*)d_out, N);
}